// Round 6
// baseline (812.514 us; speedup 1.0000x reference)
//
#include <hip/hip_runtime.h>
#include <hip/hip_bf16.h>

// SubClusteringNet: N=131072, K=16, IN=256, OUT=128
#define KEXP   16
#define IN_DIM 256
#define OUT_DIM 128
#define TILE   128        // tokens per tile
#define BPE    16         // blocks per expert (16*16 = 256 = #CUs)
#define REPS   8          // diagnostic amplification

typedef float f32x4 __attribute__((ext_vector_type(4)));
typedef short bf16x8 __attribute__((ext_vector_type(8)));
typedef const unsigned int __attribute__((address_space(1)))* gptr_t;
typedef unsigned int __attribute__((address_space(3)))* lptr_t;

__device__ __forceinline__ ushort f2bf(float f) {
    union { float f; unsigned u; } v; v.f = f;
    return (ushort)((v.u + 0x7fffu + ((v.u >> 16) & 1u)) >> 16);  // RNE
}

// ---------------- prep: W1 transpose->bf16 (pre-swizzled) + histogram ----------------
__global__ __launch_bounds__(256) void prep_k(const float* __restrict__ W1,
                                              ushort* __restrict__ w1t,
                                              const int* __restrict__ z,
                                              int* __restrict__ counts, int n) {
    __shared__ float ld[64][65];
    int bid = blockIdx.x, tid = threadIdx.x;
    if (bid < 128) {
        int e = bid >> 3, sub = bid & 7;
        int k0 = (sub & 3) * 64, n0 = (sub >> 2) * 64;
        const float* src = W1 + (long)e * (IN_DIM * OUT_DIM);   // [256][128]
        int tr = tid >> 6, tc = tid & 63;
#pragma unroll
        for (int i = 0; i < 16; i++)
            ld[i * 4 + tr][tc] = src[(k0 + i * 4 + tr) * OUT_DIM + n0 + tc];
        __syncthreads();
        char* dst = (char*)w1t + (long)e * (OUT_DIM * IN_DIM * 2);
#pragma unroll
        for (int i = 0; i < 16; i++) {
            int col = n0 + i * 4 + tr;                      // out col
            int L = (col * IN_DIM + k0 + tc) * 2;           // logical byte
            *(ushort*)(dst + (L ^ ((col & 7) << 4))) = f2bf(ld[tc][i * 4 + tr]);
        }
    } else {
        int* h = (int*)ld;
        if (tid < KEXP) h[tid] = 0;
        __syncthreads();
        for (int i = (bid - 128) * 256 + tid; i < n; i += 256 * 256)
            atomicAdd(&h[z[i]], 1);
        __syncthreads();
        if (tid < KEXP) atomicAdd(&counts[tid], h[tid]);
    }
}

// ---------------- scan ----------------
__global__ void scan_k(const int* __restrict__ counts, int* __restrict__ bases) {
    int li = threadIdx.x & 63;
    int c = (li < KEXP) ? counts[li] : 0;
    int v = c;
#pragma unroll
    for (int d = 1; d < KEXP; d <<= 1) {
        int t = __shfl_up(v, d, 64);
        if (li >= d) v += t;
    }
    if (li < KEXP) bases[li] = v - c;
}

// ---------------- scatter ----------------
__global__ __launch_bounds__(256) void scatter_k(const int* __restrict__ z,
                                                 const int* __restrict__ bases,
                                                 int* __restrict__ cursors,
                                                 int* __restrict__ perm, int n) {
    __shared__ int lc[KEXP];
    __shared__ int lb[KEXP];
    int tid = threadIdx.x;
    if (tid < KEXP) lc[tid] = 0;
    __syncthreads();
    int base = blockIdx.x * 1024 + tid;
    int e[4], r[4];
#pragma unroll
    for (int j = 0; j < 4; j++) {
        int i = base + j * 256;
        if (i < n) {
            e[j] = z[i];
            r[j] = atomicAdd(&lc[e[j]], 1);
        } else e[j] = -1;
    }
    __syncthreads();
    if (tid < KEXP && lc[tid] > 0) lb[tid] = atomicAdd(&cursors[tid], lc[tid]);
    __syncthreads();
#pragma unroll
    for (int j = 0; j < 4; j++) {
        int i = base + j * 256;
        if (i < n) perm[bases[e[j]] + lb[e[j]] + r[j]] = i;
    }
}

// ---------------- diagnostic grouped-GEMM variants ----------------
// MODE bit0 = gather+cvt+ds_write A; bit1 = MFMA compute; bit2 = real epilogue+out.
// Single A buffer, serial gather: gather and compute are never live together ->
// live set ~100 VGPR max, no spill possible. REPS x amplification; rep r covers
// tile slots (slot+r)&15 so every rep touches distinct tiles (cold-ish gather)
// and, for the full variant, every rep writes the complete correct output.
template<int MODE>
__global__ __launch_bounds__(512) void mlpv_k(
    const float* __restrict__ x, const float* __restrict__ b1,
    const float* __restrict__ W2, const float* __restrict__ b2,
    const int* __restrict__ counts, const int* __restrict__ bases,
    const int* __restrict__ perm, const ushort* __restrict__ w1t,
    float* __restrict__ out, float* __restrict__ dummy) {
    __shared__ char Wl[65536];
    __shared__ char Al[65536];

    int b = blockIdx.x;
    int e = b >> 4, slot = b & 15;
    int cnt = counts[e];
    int pb0 = bases[e];
    int ntiles = (cnt + TILE - 1) / TILE;

    int tid = threadIdx.x;
    int lane = tid & 63, w = tid >> 6;
    int li = lane & 15, q = lane >> 4;

    // stage W (64 KB) once: linear gll from pre-swizzled w1t
    const char* wsrc = (const char*)w1t + (long)e * (OUT_DIM * IN_DIM * 2);
#pragma unroll
    for (int i = 0; i < 8; i++) {
        int off = w * 8192 + i * 1024;
        __builtin_amdgcn_global_load_lds((gptr_t)(wsrc + off + lane * 16),
                                         (lptr_t)(Wl + off), 16, 0, 0);
    }

    float bbv[8], w2a[8], w2b[8];
#pragma unroll
    for (int nn = 0; nn < 8; nn++) {
        int col = nn * 16 + li;
        bbv[nn] = b1[e * OUT_DIM + col];
        w2a[nn] = W2[(e * OUT_DIM + col) * 2 + 0];
        w2b[nn] = W2[(e * OUT_DIM + col) * 2 + 1];
    }
    float bb0 = b2[e * 2 + 0], bb1 = b2[e * 2 + 1];

    float keep = 0.f;

    for (int rep = 0; rep < REPS; ++rep) {
        int sl = (slot + rep) & 15;
        for (int t = sl; t < ntiles; t += BPE) {
            int nr = cnt - t * TILE;
            int pb = pb0 + t * TILE;

            if constexpr (MODE & 1) {
                int rr = w * 16 + li;
                int pv = perm[pb + (rr < nr ? rr : nr - 1)];
                f32x4 av[16];
#pragma unroll
                for (int i = 0; i < 16; i++) {
                    int g = __shfl(pv, i, 16);
                    av[i] = *(const f32x4*)((const char*)x + (long)g * 1024 + lane * 16);
                }
#pragma unroll
                for (int i = 0; i < 16; i++) {
                    uint2 pk;
                    pk.x = (unsigned)f2bf(av[i][0]) | ((unsigned)f2bf(av[i][1]) << 16);
                    pk.y = (unsigned)f2bf(av[i][2]) | ((unsigned)f2bf(av[i][3]) << 16);
                    int r = w * 16 + i;
                    *(uint2*)(Al + r * 512 + ((lane * 8) ^ ((r & 7) << 4))) = pk;
                }
            }
            __syncthreads();

            f32x4 acc[8];
#pragma unroll
            for (int nn = 0; nn < 8; nn++) acc[nn] = (f32x4)0.0f;

            if constexpr (MODE & 2) {
                int arow = w * 16 + li;
                int aswz = (arow & 7) << 4;
#pragma unroll
                for (int kk = 0; kk < 8; kk++) {
                    bf16x8 af = *(const bf16x8*)(Al + arow * 512 + ((kk * 64 + q * 16) ^ aswz));
#pragma unroll
                    for (int nn = 0; nn < 8; nn++) {
                        int col = nn * 16 + li;
                        bf16x8 bf = *(const bf16x8*)(Wl + col * 512 + ((kk * 64 + q * 16) ^ ((col & 7) << 4)));
                        acc[nn] = __builtin_amdgcn_mfma_f32_16x16x32_bf16(af, bf, acc[nn], 0, 0, 0);
                    }
                }
            }

            if constexpr (MODE & 4) {
                float p0[4] = {0.f, 0.f, 0.f, 0.f}, p1[4] = {0.f, 0.f, 0.f, 0.f};
#pragma unroll
                for (int nn = 0; nn < 8; nn++) {
#pragma unroll
                    for (int r = 0; r < 4; r++) {
                        float h = fmaxf(acc[nn][r] + bbv[nn], 0.0f);
                        p0[r] += h * w2a[nn];
                        p1[r] += h * w2b[nn];
                    }
                }
#pragma unroll
                for (int m = 1; m < 16; m <<= 1)
#pragma unroll
                    for (int r = 0; r < 4; r++) {
                        p0[r] += __shfl_xor(p0[r], m, 64);
                        p1[r] += __shfl_xor(p1[r], m, 64);
                    }
                if (li == 0) {
#pragma unroll
                    for (int r = 0; r < 4; r++) {
                        int mm = w * 16 + q * 4 + r;
                        if (mm < nr) {
                            int orig = perm[pb + mm];
                            float l0 = p0[r] + bb0, l1 = p1[r] + bb1;
                            float mx = fmaxf(l0, l1);
                            float e0 = __expf(l0 - mx), e1 = __expf(l1 - mx);
                            float inv = 1.0f / (e0 + e1);
                            *(float2*)(out + (long)orig * 2) = make_float2(e0 * inv, e1 * inv);
                        }
                    }
                }
            } else {
                // keepalive: real LDS read (keeps ds_writes) + acc chain (keeps MFMA)
                keep += *(const float*)(Al + ((tid * 4) & 65532));
#pragma unroll
                for (int nn = 0; nn < 8; nn++)
                    keep += acc[nn][0] + acc[nn][1] + acc[nn][2] + acc[nn][3];
            }
            __syncthreads();
        }
    }
    if constexpr (!(MODE & 4)) dummy[b * 512 + tid] = keep;
}

extern "C" void kernel_launch(void* const* d_in, const int* in_sizes, int n_in,
                              void* d_out, int out_size, void* d_ws, size_t ws_size,
                              hipStream_t stream) {
    const float* x  = (const float*)d_in[0];
    const int*   z  = (const int*)d_in[1];
    const float* W1 = (const float*)d_in[2];
    const float* b1 = (const float*)d_in[3];
    const float* W2 = (const float*)d_in[4];
    const float* b2 = (const float*)d_in[5];
    float* out = (float*)d_out;
    int n = in_sizes[1];                    // 131072 tokens

    int* counts  = (int*)d_ws;
    int* cursors = counts + 16;
    int* basesp  = counts + 32;
    int* perm    = counts + 256;                                  // byte offset 1024
    ushort* w1t  = (ushort*)((char*)d_ws + 1024 + (size_t)n * 4); // 16B-aligned
    float* dummy = (float*)((char*)d_ws + (8u << 20));            // 8 MB offset scratch

    hipMemsetAsync(counts, 0, 128, stream);
    prep_k<<<384, 256, 0, stream>>>(W1, w1t, z, counts, n);
    scan_k<<<1, 64, 0, stream>>>(counts, basesp);
    scatter_k<<<(n + 1023) / 1024, 256, 0, stream>>>(z, basesp, cursors, perm, n);

    // diagnostics (x8 amplified), then the real thing last (also x8, idempotent)
    mlpv_k<1><<<KEXP * BPE, 512, 0, stream>>>(x, b1, W2, b2, counts, basesp, perm, w1t, out, dummy);
    mlpv_k<2><<<KEXP * BPE, 512, 0, stream>>>(x, b1, W2, b2, counts, basesp, perm, w1t, out, dummy);
    mlpv_k<3><<<KEXP * BPE, 512, 0, stream>>>(x, b1, W2, b2, counts, basesp, perm, w1t, out, dummy);
    mlpv_k<7><<<KEXP * BPE, 512, 0, stream>>>(x, b1, W2, b2, counts, basesp, perm, w1t, out, dummy);
}

// Round 7
// 268.303 us; speedup vs baseline: 3.0283x; 3.0283x over previous
//
#include <hip/hip_runtime.h>
#include <hip/hip_bf16.h>

// SubClusteringNet: N=131072, K=16, IN=256, OUT=128
// Stream-and-locally-bucket design: NO global permutation / gather.
#define KEXP    16
#define IN_DIM  256
#define OUT_DIM 128
#define CHUNK   128      // tokens per block (contiguous!)
#define MAXT    24       // max padded 16-row m-tiles per chunk (16 + 112/16 = 23)

typedef float f32x4 __attribute__((ext_vector_type(4)));
typedef short bf16x8 __attribute__((ext_vector_type(8)));

__device__ __forceinline__ ushort f2bf(float f) {
    union { float f; unsigned u; } v; v.f = f;
    return (ushort)((v.u + 0x7fffu + ((v.u >> 16) & 1u)) >> 16);  // RNE
}

// ---------------- prep: W1 [K][256][128] f32 -> MFMA-fragment layout bf16 ----------------
// w1frag[e][kk][nn][lane][8 bf16]: lane l of fragment (kk,nn) holds
// W1[k = kk*32 + (l>>4)*8 + j][col = nn*16 + (l&15)], j=0..7. So the mlp's B-load
// is ONE contiguous 1KB coalesced read (base + lane*16) -- L2-resident (1 MB total).
__global__ __launch_bounds__(256) void prep_k(const float* __restrict__ W1,
                                              ushort* __restrict__ w1frag) {
    __shared__ float ld[64][65];
    int bid = blockIdx.x, tid = threadIdx.x;      // 128 blocks: e(16) x k0(4) x n0(2)
    int e = bid >> 3, sub = bid & 7;
    int k0 = (sub & 3) * 64, n0 = (sub >> 2) * 64;
    const float* src = W1 + (long)e * (IN_DIM * OUT_DIM);   // [256][128]
    int tr = tid >> 6, tc = tid & 63;
#pragma unroll
    for (int i = 0; i < 16; i++)
        ld[i * 4 + tr][tc] = src[(k0 + i * 4 + tr) * OUT_DIM + n0 + tc];
    __syncthreads();
#pragma unroll
    for (int i = 0; i < 16; i++) {
        int col = n0 + i * 4 + tr;          // 0..127
        int k   = k0 + tc;                  // 0..255
        int kk = k >> 5, q = (k >> 3) & 3, j = k & 7;
        int li = col & 15, nn = col >> 4, lane = q * 16 + li;
        long byte = ((((long)e * 8 + kk) * 8 + nn) * 64 + lane) * 16 + j * 2;
        *(ushort*)((char*)w1frag + byte) = f2bf(ld[tc][i * 4 + tr]);
    }
}

// ---------------- main: stream chunk -> local bucket -> MFMA -> head -> softmax ----------------
// 1024 blocks x 512 thr (8 waves). LDS ~67KB -> 2 blocks/CU; (512,4) caps VGPR at 128
// so both blocks resident -> stream phase of one overlaps compute phase of the other.
__global__ __launch_bounds__(512, 4) void moe_k(
    const float* __restrict__ x, const int* __restrict__ z,
    const float* __restrict__ b1, const float* __restrict__ W2,
    const float* __restrict__ b2, const ushort* __restrict__ w1frag,
    float* __restrict__ out, int n) {
    __shared__ __align__(16) char Al[CHUNK * 512];   // 64 KB bf16 A, swizzled rows
    __shared__ int lrow[CHUNK];     // token t (chunk-local) -> bucketed LDS row
    __shared__ int lorig[CHUNK];    // bucketed row -> global token index
    __shared__ int hist[KEXP], cur[KEXP];
    __shared__ int t_e[MAXT], t_row[MAXT], t_cnt[MAXT];
    __shared__ int ntile_s;

    int tid = threadIdx.x;
    int lane = tid & 63, w = tid >> 6;
    int li = lane & 15, q = lane >> 4;
    int chunk0 = blockIdx.x * CHUNK;

    // ---- phase 1: bucket the chunk's tokens by expert (all in LDS) ----
    if (tid < KEXP) hist[tid] = 0;
    __syncthreads();
    int e_t = -1;
    if (tid < CHUNK) {
        e_t = z[chunk0 + tid];
        atomicAdd(&hist[e_t], 1);
    }
    __syncthreads();
    if (tid == 0) {
        int a = 0, nt = 0;
        for (int e = 0; e < KEXP; e++) {
            int c = hist[e];
            cur[e] = a;
            for (int j = 0; j < c; j += 16) {
                t_e[nt] = e; t_row[nt] = a + j; t_cnt[nt] = min(16, c - j); nt++;
            }
            a += c;
        }
        ntile_s = nt;
    }
    __syncthreads();
    if (tid < CHUNK) {
        int r = atomicAdd(&cur[e_t], 1);
        lrow[tid] = r;
        lorig[r] = chunk0 + tid;
    }
    __syncthreads();

    // ---- phase 2: stream x rows (perfectly coalesced), cvt bf16, swizzled ds_write ----
    int lr[16];
#pragma unroll
    for (int i = 0; i < 16; i++) lr[i] = lrow[i * 8 + w];   // broadcast reads
#pragma unroll
    for (int i = 0; i < 16; i++) {
        int row = i * 8 + w;                                // wave-uniform source row
        f32x4 v = *(const f32x4*)(x + ((long)chunk0 + row) * IN_DIM + lane * 4);
        uint2 pk;
        pk.x = (unsigned)f2bf(v[0]) | ((unsigned)f2bf(v[1]) << 16);
        pk.y = (unsigned)f2bf(v[2]) | ((unsigned)f2bf(v[3]) << 16);
        int r = lr[i];
        *(uint2*)(Al + r * 512 + ((lane * 8) ^ ((r & 7) << 4))) = pk;
    }
    __syncthreads();

    // ---- phase 3: m-tiles; wave w takes tiles w, w+8, ... ----
    int ntile = ntile_s;
    for (int ti = w; ti < ntile; ti += 8) {
        int e = t_e[ti], rbase = t_row[ti], cnt = t_cnt[ti];

        // A-fragment row for this lane (dup last row for padding)
        int arow = rbase + (li < cnt ? li : cnt - 1);
        int aswz = (arow & 7) << 4;

        const char* wf = (const char*)w1frag + ((long)e * 64) * 1024 + lane * 16;

        f32x4 acc[8];
#pragma unroll
        for (int nn = 0; nn < 8; nn++) acc[nn] = (f32x4)0.0f;

#pragma unroll
        for (int kk = 0; kk < 8; kk++) {
            bf16x8 af = *(const bf16x8*)(Al + arow * 512 + ((kk * 64 + q * 16) ^ aswz));
#pragma unroll
            for (int nn = 0; nn < 8; nn++) {
                bf16x8 bf = *(const bf16x8*)(wf + (long)(kk * 8 + nn) * 1024);
                acc[nn] = __builtin_amdgcn_mfma_f32_16x16x32_bf16(af, bf, acc[nn], 0, 0, 0);
            }
        }

        // epilogue: relu + 128->2 head + softmax; 16-lane butterfly over li
        float p0[4] = {0.f, 0.f, 0.f, 0.f}, p1[4] = {0.f, 0.f, 0.f, 0.f};
#pragma unroll
        for (int nn = 0; nn < 8; nn++) {
            int col = nn * 16 + li;
            float bb = b1[e * OUT_DIM + col];
            float wa = W2[(e * OUT_DIM + col) * 2 + 0];
            float wb = W2[(e * OUT_DIM + col) * 2 + 1];
#pragma unroll
            for (int r = 0; r < 4; r++) {
                float h = fmaxf(acc[nn][r] + bb, 0.0f);
                p0[r] += h * wa;
                p1[r] += h * wb;
            }
        }
#pragma unroll
        for (int m = 1; m < 16; m <<= 1)
#pragma unroll
            for (int r = 0; r < 4; r++) {
                p0[r] += __shfl_xor(p0[r], m, 64);
                p1[r] += __shfl_xor(p1[r], m, 64);
            }
        if (li == 0) {
            float bb0 = b2[e * 2 + 0], bb1 = b2[e * 2 + 1];
#pragma unroll
            for (int r = 0; r < 4; r++) {
                int m = q * 4 + r;
                if (m < cnt) {
                    int orig = lorig[rbase + m];
                    float l0 = p0[r] + bb0, l1 = p1[r] + bb1;
                    float mx = fmaxf(l0, l1);
                    float e0 = __expf(l0 - mx), e1 = __expf(l1 - mx);
                    float inv = 1.0f / (e0 + e1);
                    *(float2*)(out + (long)orig * 2) = make_float2(e0 * inv, e1 * inv);
                }
            }
        }
    }
}

extern "C" void kernel_launch(void* const* d_in, const int* in_sizes, int n_in,
                              void* d_out, int out_size, void* d_ws, size_t ws_size,
                              hipStream_t stream) {
    const float* x  = (const float*)d_in[0];
    const int*   z  = (const int*)d_in[1];
    const float* W1 = (const float*)d_in[2];
    const float* b1 = (const float*)d_in[3];
    const float* W2 = (const float*)d_in[4];
    const float* b2 = (const float*)d_in[5];
    float* out = (float*)d_out;
    int n = in_sizes[1];                     // 131072 tokens

    ushort* w1frag = (ushort*)d_ws;          // 1 MB fragment-layout weights

    prep_k<<<128, 256, 0, stream>>>(W1, w1frag);
    moe_k<<<n / CHUNK, 512, 0, stream>>>(x, z, b1, W2, b2, w1frag, out, n);
}

// Round 8
// 242.862 us; speedup vs baseline: 3.3456x; 1.1048x over previous
//
#include <hip/hip_runtime.h>
#include <hip/hip_bf16.h>

// SubClusteringNet: N=131072, K=16, IN=256, OUT=128
// Stream-and-locally-bucket: no global permutation/gather (R7 structure),
// spill-free register budget + pipelined B-loads (R8 fix).
#define KEXP    16
#define IN_DIM  256
#define OUT_DIM 128
#define CHUNK   128      // tokens per block (contiguous)
#define MAXT    24       // max padded 16-row m-tiles per chunk

typedef float f32x4 __attribute__((ext_vector_type(4)));
typedef short bf16x8 __attribute__((ext_vector_type(8)));

__device__ __forceinline__ ushort f2bf(float f) {
    union { float f; unsigned u; } v; v.f = f;
    return (ushort)((v.u + 0x7fffu + ((v.u >> 16) & 1u)) >> 16);  // RNE
}

// ---------------- prep: W1 [K][256][128] f32 -> MFMA-fragment layout bf16 ----------------
// w1frag[e][kk][nn][lane][8 bf16]: lane l of fragment (kk,nn) holds
// W1[k = kk*32 + (l>>4)*8 + j][col = nn*16 + (l&15)], j=0..7. B-load in moe_k is
// ONE contiguous 1KB coalesced read (base + lane*16) -- L2-resident (1 MB total).
__global__ __launch_bounds__(256) void prep_k(const float* __restrict__ W1,
                                              ushort* __restrict__ w1frag) {
    __shared__ float ld[64][65];
    int bid = blockIdx.x, tid = threadIdx.x;      // 128 blocks: e(16) x k0(4) x n0(2)
    int e = bid >> 3, sub = bid & 7;
    int k0 = (sub & 3) * 64, n0 = (sub >> 2) * 64;
    const float* src = W1 + (long)e * (IN_DIM * OUT_DIM);   // [256][128]
    int tr = tid >> 6, tc = tid & 63;
#pragma unroll
    for (int i = 0; i < 16; i++)
        ld[i * 4 + tr][tc] = src[(k0 + i * 4 + tr) * OUT_DIM + n0 + tc];
    __syncthreads();
#pragma unroll
    for (int i = 0; i < 16; i++) {
        int col = n0 + i * 4 + tr;          // 0..127
        int k   = k0 + tc;                  // 0..255
        int kk = k >> 5, q = (k >> 3) & 3, j = k & 7;
        int li = col & 15, nn = col >> 4, lane = q * 16 + li;
        long byte = ((((long)e * 8 + kk) * 8 + nn) * 64 + lane) * 16 + j * 2;
        *(ushort*)((char*)w1frag + byte) = f2bf(ld[tc][i * 4 + tr]);
    }
}

// ---------------- main: stream chunk -> local bucket -> MFMA -> head -> softmax ----------------
// 1024 blocks x 512 thr (8 waves). LDS ~65.7KB -> 2 blocks/CU if VGPR<=128.
// (512,2): cap 256 VGPR -> compiler lands ~100-125 naturally, NO spills (the R7 killer).
__global__ __launch_bounds__(512, 2) void moe_k(
    const float* __restrict__ x, const int* __restrict__ z,
    const float* __restrict__ b1, const float* __restrict__ W2,
    const float* __restrict__ b2, const ushort* __restrict__ w1frag,
    float* __restrict__ out, int n) {
    __shared__ __align__(16) char Al[CHUNK * 512];   // 64 KB bf16 A, swizzled rows
    __shared__ int lrow[CHUNK];     // chunk-local token -> bucketed LDS row
    __shared__ int lorig[CHUNK];    // bucketed row -> global token index
    __shared__ int hist[KEXP], cur[KEXP];
    __shared__ int t_e[MAXT], t_row[MAXT], t_cnt[MAXT];
    __shared__ int ntile_s;

    int tid = threadIdx.x;
    int lane = tid & 63, w = tid >> 6;
    int li = lane & 15, q = lane >> 4;
    int chunk0 = blockIdx.x * CHUNK;

    // ---- phase 1: bucket the chunk's tokens by expert (all in LDS) ----
    if (tid < KEXP) hist[tid] = 0;
    __syncthreads();
    int e_t = -1;
    if (tid < CHUNK) {
        e_t = z[chunk0 + tid];
        atomicAdd(&hist[e_t], 1);
    }
    __syncthreads();
    if (tid == 0) {
        int a = 0, nt = 0;
        for (int e = 0; e < KEXP; e++) {
            int c = hist[e];
            cur[e] = a;
            for (int j = 0; j < c; j += 16) {
                t_e[nt] = e; t_row[nt] = a + j; t_cnt[nt] = min(16, c - j); nt++;
            }
            a += c;
        }
        ntile_s = nt;
    }
    __syncthreads();
    if (tid < CHUNK) {
        int r = atomicAdd(&cur[e_t], 1);
        lrow[tid] = r;
        lorig[r] = chunk0 + tid;
    }
    __syncthreads();

    // ---- phase 2: stream x rows (coalesced 1KB/wave-instr), cvt bf16, swizzled ds_write ----
    // One row per iteration, unroll 4: ~30 live regs, 4 loads in flight.
#pragma unroll 4
    for (int i = 0; i < 16; i++) {
        int row = i * 8 + w;                                // wave-uniform source row
        int r = lrow[row];
        f32x4 v = *(const f32x4*)(x + ((long)chunk0 + row) * IN_DIM + lane * 4);
        uint2 pk;
        pk.x = (unsigned)f2bf(v[0]) | ((unsigned)f2bf(v[1]) << 16);
        pk.y = (unsigned)f2bf(v[2]) | ((unsigned)f2bf(v[3]) << 16);
        *(uint2*)(Al + r * 512 + ((lane * 8) ^ ((r & 7) << 4))) = pk;
    }
    __syncthreads();

    // ---- phase 3: m-tiles; wave w takes tiles w, w+8; B double-buffered from L2 ----
    int ntile = ntile_s;
    for (int ti = w; ti < ntile; ti += 8) {
        int e = t_e[ti], rbase = t_row[ti], cnt = t_cnt[ti];

        int arow = rbase + (li < cnt ? li : cnt - 1);       // dup last row as padding
        int aswz = (arow & 7) << 4;

        const char* wf = (const char*)w1frag + ((long)e * 64) * 1024 + lane * 16;

        f32x4 acc[8];
#pragma unroll
        for (int nn = 0; nn < 8; nn++) acc[nn] = (f32x4)0.0f;

        // ping-pong B-fragment buffers (static indexing only)
        bf16x8 bA[8], bB[8];
#pragma unroll
        for (int nn = 0; nn < 8; nn++) bA[nn] = *(const bf16x8*)(wf + (long)nn * 1024);

#pragma unroll
        for (int kk = 0; kk < 8; kk += 2) {
            // prefetch kk+1 into bB while computing kk from bA
            if (kk + 1 < 8) {
#pragma unroll
                for (int nn = 0; nn < 8; nn++)
                    bB[nn] = *(const bf16x8*)(wf + (long)((kk + 1) * 8 + nn) * 1024);
            }
            {
                bf16x8 af = *(const bf16x8*)(Al + arow * 512 + ((kk * 64 + q * 16) ^ aswz));
#pragma unroll
                for (int nn = 0; nn < 8; nn++)
                    acc[nn] = __builtin_amdgcn_mfma_f32_16x16x32_bf16(af, bA[nn], acc[nn], 0, 0, 0);
            }
            // prefetch kk+2 into bA while computing kk+1 from bB
            if (kk + 2 < 8) {
#pragma unroll
                for (int nn = 0; nn < 8; nn++)
                    bA[nn] = *(const bf16x8*)(wf + (long)((kk + 2) * 8 + nn) * 1024);
            }
            {
                bf16x8 af = *(const bf16x8*)(Al + arow * 512 + (((kk + 1) * 64 + q * 16) ^ aswz));
#pragma unroll
                for (int nn = 0; nn < 8; nn++)
                    acc[nn] = __builtin_amdgcn_mfma_f32_16x16x32_bf16(af, bB[nn], acc[nn], 0, 0, 0);
            }
        }

        // epilogue: relu + 128->2 head + softmax; 16-lane butterfly over li
        float p0[4] = {0.f, 0.f, 0.f, 0.f}, p1[4] = {0.f, 0.f, 0.f, 0.f};
#pragma unroll
        for (int nn = 0; nn < 8; nn++) {
            int col = nn * 16 + li;
            float bb = b1[e * OUT_DIM + col];
            float wa = W2[(e * OUT_DIM + col) * 2 + 0];
            float wb = W2[(e * OUT_DIM + col) * 2 + 1];
#pragma unroll
            for (int r = 0; r < 4; r++) {
                float h = fmaxf(acc[nn][r] + bb, 0.0f);
                p0[r] += h * wa;
                p1[r] += h * wb;
            }
        }
#pragma unroll
        for (int m = 1; m < 16; m <<= 1)
#pragma unroll
            for (int r = 0; r < 4; r++) {
                p0[r] += __shfl_xor(p0[r], m, 64);
                p1[r] += __shfl_xor(p1[r], m, 64);
            }
        if (li == 0) {
            float bb0 = b2[e * 2 + 0], bb1 = b2[e * 2 + 1];
#pragma unroll
            for (int r = 0; r < 4; r++) {
                int m = q * 4 + r;
                if (m < cnt) {
                    int orig = lorig[rbase + m];
                    float l0 = p0[r] + bb0, l1 = p1[r] + bb1;
                    float mx = fmaxf(l0, l1);
                    float e0 = __expf(l0 - mx), e1 = __expf(l1 - mx);
                    float inv = 1.0f / (e0 + e1);
                    *(float2*)(out + (long)orig * 2) = make_float2(e0 * inv, e1 * inv);
                }
            }
        }
    }
}

extern "C" void kernel_launch(void* const* d_in, const int* in_sizes, int n_in,
                              void* d_out, int out_size, void* d_ws, size_t ws_size,
                              hipStream_t stream) {
    const float* x  = (const float*)d_in[0];
    const int*   z  = (const int*)d_in[1];
    const float* W1 = (const float*)d_in[2];
    const float* b1 = (const float*)d_in[3];
    const float* W2 = (const float*)d_in[4];
    const float* b2 = (const float*)d_in[5];
    float* out = (float*)d_out;
    int n = in_sizes[1];                     // 131072 tokens

    ushort* w1frag = (ushort*)d_ws;          // 1 MB fragment-layout weights

    prep_k<<<128, 256, 0, stream>>>(W1, w1frag);
    moe_k<<<n / CHUNK, 512, 0, stream>>>(x, z, b1, W2, b2, w1frag, out, n);
}